// Round 3
// baseline (2539.734 us; speedup 1.0000x reference)
//
#include <hip/hip_runtime.h>
#include <hip/hip_fp16.h>

// LSTM B=256,T=512,IN=64,H=128,L=2 + FC. One block per batch element, 256 blocks.
// 1024 threads = 512 gate rows x 2 K-halves. Resident fp16 weights per thread:
// whh0-half(32) + wih1-half(32) + whh1-half(32) = 96 VGPRs. wih0 in LDS as
// per-thread 64B chunks at stride 80B (bank-conflict-free, b128-aligned).
// LDS total 87.3KB > 80KB => hardware-guaranteed 1 block/CU, and
// amdgpu_waves_per_eu(4,4) => allocator budget 128 VGPRs => no spills.
// Layers software-pipelined (L0(t) + L1(t-1)), 2 barriers/step.

#define BB 256
#define TT 512
#define HH 128

typedef _Float16 f16x2 __attribute__((ext_vector_type(2)));
typedef _Float16 f16x8 __attribute__((ext_vector_type(8)));

__device__ __forceinline__ f16x2 cvt2(float a, float b) {
    f16x2 r; r.x = (_Float16)a; r.y = (_Float16)b; return r;
}

__device__ __forceinline__ float fdot2_(f16x2 a, f16x2 b, float c) {
#if __has_builtin(__builtin_amdgcn_fdot2)
    return __builtin_amdgcn_fdot2(a, b, c, false);
#else
    return c + (float)a.x * (float)b.x + (float)a.y * (float)b.y;
#endif
}

#define SH2(v, i) __builtin_shufflevector(v, v, 2*(i), 2*(i)+1)

__device__ __forceinline__ float tanh_f(float x) {
    float e = __expf(2.0f * x);
    return 1.0f - 2.0f * __builtin_amdgcn_rcpf(e + 1.0f);
}

__global__ __attribute__((amdgpu_waves_per_eu(4, 4))) __launch_bounds__(1024)
void lstm_fused(
    const float* __restrict__ x,
    const float* __restrict__ w_ih0, const float* __restrict__ w_hh0,
    const float* __restrict__ b_ih0, const float* __restrict__ b_hh0,
    const float* __restrict__ w_ih1, const float* __restrict__ w_hh1,
    const float* __restrict__ b_ih1, const float* __restrict__ b_hh1,
    const float* __restrict__ fc_w, const float* __restrict__ fc_b,
    float* __restrict__ out)
{
    const int tid = threadIdx.x;
    const int b   = blockIdx.x;
    const int row = tid >> 1;   // gate row 0..511
    const int s   = tid & 1;    // K-half

    __shared__ __align__(16) unsigned char wih0s[1024 * 80]; // 81920 B, stride-80 chunks
    __shared__ __align__(16) f16x2 h0sh[HH / 2];             // 256 B
    __shared__ __align__(16) f16x2 h1sh[HH / 2];             // 256 B
    __shared__ __align__(16) f16x2 xsh[2][32];               // 256 B (dbuf x_t fp16)
    __shared__ float gl0[512];
    __shared__ float gl1[512];
    __shared__ float h1f[HH];

    // ---- per-thread resident weights (fp16 halves of rows) ----
    f16x2 whh0h[32], wih1h[32], whh1h[32];
    {
        const float4* p = (const float4*)(w_hh0 + row * HH + s * 64);
        #pragma unroll
        for (int k = 0; k < 16; ++k) {
            float4 v = p[k];
            whh0h[2 * k]     = cvt2(v.x, v.y);
            whh0h[2 * k + 1] = cvt2(v.z, v.w);
        }
    }
    {
        const float4* p = (const float4*)(w_ih1 + row * HH + s * 64);
        #pragma unroll
        for (int k = 0; k < 16; ++k) {
            float4 v = p[k];
            wih1h[2 * k]     = cvt2(v.x, v.y);
            wih1h[2 * k + 1] = cvt2(v.z, v.w);
        }
    }
    {
        const float4* p = (const float4*)(w_hh1 + row * HH + s * 64);
        #pragma unroll
        for (int k = 0; k < 16; ++k) {
            float4 v = p[k];
            whh1h[2 * k]     = cvt2(v.x, v.y);
            whh1h[2 * k + 1] = cvt2(v.z, v.w);
        }
    }
    // ---- wih0 -> LDS: thread's own K-half chunk (64B) at stride 80B ----
    {
        const float4* p = (const float4*)(w_ih0 + row * 64 + s * 32); // 8 float4
        f16x2* dst = (f16x2*)(wih0s + tid * 80);
        #pragma unroll
        for (int k = 0; k < 8; ++k) {
            float4 v = p[k];
            dst[2 * k]     = cvt2(v.x, v.y);
            dst[2 * k + 1] = cvt2(v.z, v.w);
        }
    }
    const float mybias = (s == 0) ? (b_ih0[row] + b_hh0[row])
                                  : (b_ih1[row] + b_hh1[row]);

    if (tid < 64)        h0sh[tid] = cvt2(0.f, 0.f);
    else if (tid < 128)  h1sh[tid - 64] = cvt2(0.f, 0.f);
    else if (tid >= 256 && tid < 272) {
        int q = tid - 256;
        float4 v = ((const float4*)x)[(b * TT + 0) * 16 + q];
        xsh[0][2 * q]     = cvt2(v.x, v.y);
        xsh[0][2 * q + 1] = cvt2(v.z, v.w);
    }
    float c0 = 0.f, c1 = 0.f;
    __syncthreads();

    const f16x8* __restrict__ wv = (const f16x8*)(wih0s + tid * 80); // 4 chunks
    const f16x8* __restrict__ h0v = (const f16x8*)((const char*)h0sh + s * 128);
    const f16x8* __restrict__ h1v = (const f16x8*)((const char*)h1sh + s * 128);

    #pragma unroll 1
    for (int t = 0; t <= TT; ++t) {
        const f16x8* __restrict__ xv =
            (const f16x8*)((const char*)xsh[t & 1] + s * 64);

        // ---- dot phase: L0(t) and L1(t-1) partial preacts (this K-half) ----
        float a0 = 0.f, a1 = 0.f, p0 = 0.f, p1 = 0.f;
        #pragma unroll
        for (int c = 0; c < 8; ++c) {        // h0 . {whh0 (L0), wih1 (L1)}
            f16x8 h = h0v[c];
            a0 = fdot2_(SH2(h, 0), whh0h[4 * c + 0], a0);
            p0 = fdot2_(SH2(h, 0), wih1h[4 * c + 0], p0);
            a1 = fdot2_(SH2(h, 1), whh0h[4 * c + 1], a1);
            p1 = fdot2_(SH2(h, 1), wih1h[4 * c + 1], p1);
            a0 = fdot2_(SH2(h, 2), whh0h[4 * c + 2], a0);
            p0 = fdot2_(SH2(h, 2), wih1h[4 * c + 2], p0);
            a1 = fdot2_(SH2(h, 3), whh0h[4 * c + 3], a1);
            p1 = fdot2_(SH2(h, 3), wih1h[4 * c + 3], p1);
        }
        #pragma unroll
        for (int c = 0; c < 8; ++c) {        // h1 . whh1 (L1)
            f16x8 h = h1v[c];
            p0 = fdot2_(SH2(h, 0), whh1h[4 * c + 0], p0);
            p1 = fdot2_(SH2(h, 1), whh1h[4 * c + 1], p1);
            p0 = fdot2_(SH2(h, 2), whh1h[4 * c + 2], p0);
            p1 = fdot2_(SH2(h, 3), whh1h[4 * c + 3], p1);
        }
        #pragma unroll
        for (int g = 0; g < 4; ++g) {        // x . wih0 (L0), weights from LDS
            f16x8 w = wv[g];
            f16x8 xc = xv[g];
            a0 = fdot2_(SH2(xc, 0), SH2(w, 0), a0);
            a1 = fdot2_(SH2(xc, 1), SH2(w, 1), a1);
            a0 = fdot2_(SH2(xc, 2), SH2(w, 2), a0);
            a1 = fdot2_(SH2(xc, 3), SH2(w, 3), a1);
        }
        float l0 = a0 + a1; l0 += __shfl_xor(l0, 1, 64);
        float l1 = p0 + p1; l1 += __shfl_xor(l1, 1, 64);
        {
            float z = ((s == 0) ? l0 : l1) + mybias;
            bool isg = (row >= 256) & (row < 384);      // g-gate -> tanh
            float zz = isg ? 2.f * z : z;
            float e  = __expf(-zz);
            float sg = __builtin_amdgcn_rcpf(1.f + e);  // sigmoid(zz)
            float act = isg ? 2.f * sg - 1.f : sg;      // tanh via sigmoid
            if (s == 0) gl0[row] = act; else gl1[row] = act;
        }
        __syncthreads();  // B1

        // ---- update phase ----
        if (tid < 128) {                    // L0 state (valid for t < TT)
            if (t < TT) {
                float gi = gl0[tid], gf = gl0[tid + 128];
                float gg = gl0[tid + 256], go = gl0[tid + 384];
                c0 = gf * c0 + gi * gg;
                float hh = go * tanh_f(c0);
                ((_Float16*)h0sh)[tid] = (_Float16)hh;
            }
        } else if (tid < 256) {             // L1 state for time t-1 (t >= 1)
            if (t >= 1) {
                int j = tid - 128;
                float gi = gl1[j], gf = gl1[j + 128];
                float gg = gl1[j + 256], go = gl1[j + 384];
                c1 = gf * c1 + gi * gg;
                float hh = go * tanh_f(c1);
                ((_Float16*)h1sh)[j] = (_Float16)hh;
                if (t == TT) h1f[j] = hh;
            }
        } else if (tid < 272) {             // prefetch x(t+1)
            if (t + 1 < TT) {
                int q = tid - 256;
                float4 v = ((const float4*)x)[(b * TT + t + 1) * 16 + q];
                xsh[(t + 1) & 1][2 * q]     = cvt2(v.x, v.y);
                xsh[(t + 1) & 1][2 * q + 1] = cvt2(v.z, v.w);
            }
        }
        __syncthreads();  // B2
    }

    // ---- FC epilogue ----
    if (tid < 64) {
        float p = h1f[tid] * fc_w[tid] + h1f[tid + 64] * fc_w[tid + 64];
        #pragma unroll
        for (int off = 32; off > 0; off >>= 1) p += __shfl_down(p, off, 64);
        if (tid == 0) out[b] = p + fc_b[0];
    }
}

extern "C" void kernel_launch(void* const* d_in, const int* in_sizes, int n_in,
                              void* d_out, int out_size, void* d_ws, size_t ws_size,
                              hipStream_t stream) {
    const float* x     = (const float*)d_in[0];
    const float* w_ih0 = (const float*)d_in[1];
    const float* w_hh0 = (const float*)d_in[2];
    const float* b_ih0 = (const float*)d_in[3];
    const float* b_hh0 = (const float*)d_in[4];
    const float* w_ih1 = (const float*)d_in[5];
    const float* w_hh1 = (const float*)d_in[6];
    const float* b_ih1 = (const float*)d_in[7];
    const float* b_hh1 = (const float*)d_in[8];
    const float* fc_w  = (const float*)d_in[9];
    const float* fc_b  = (const float*)d_in[10];
    float* out = (float*)d_out;

    lstm_fused<<<dim3(BB), dim3(1024), 0, stream>>>(
        x, w_ih0, w_hh0, b_ih0, b_hh0, w_ih1, w_hh1, b_ih1, b_hh1,
        fc_w, fc_b, out);
}

// Round 4
// 922.259 us; speedup vs baseline: 2.7538x; 2.7538x over previous
//
#include <hip/hip_runtime.h>
#include <hip/hip_fp16.h>

// LSTM B=256,T=512,IN=64,H=128,L=2 + FC, restructured as:
//  K0 cvt       : x, w_ih0, w_ih1 -> fp16 (ws)
//  KG (MFMA)    : xg0 = x16.Wih0^T + bias   [131072,512] fp16 (ws)
//  KR (L0)      : recurrent, whh0 in regs (64 VGPR), writes h0_all fp16 (ws)
//  KG (MFMA)    : xg1 = h0_all.Wih1^T + bias (overwrites xg buffer)
//  KR (L1)      : recurrent + fused FC -> out
// KR: 256 blocks x 512 thr, thread=gate row r with K-half s=r&1; holds rows
// (r, r^1) half-s weights = 64 VGPRs; 8 ds_read_b128 h-broadcasts (2-addr =
// free 2-way), 64 v_dot2_f32_f16, shfl_xor(1) partial combine, 2 barriers.
// __launch_bounds__(512,2) = the config that measured VGPR_Count=128 (R1).

#define TT 512
#define MM (256 * 512)   // 131072 rows for the batched GEMMs

typedef _Float16 f16x2 __attribute__((ext_vector_type(2)));
typedef _Float16 f16x8 __attribute__((ext_vector_type(8)));
typedef float f32x4 __attribute__((ext_vector_type(4)));

#define SH2(v, i) __builtin_shufflevector(v, v, 2*(i), 2*(i)+1)

__device__ __forceinline__ float fdot2_(f16x2 a, f16x2 b, float c) {
    return __builtin_amdgcn_fdot2(a, b, c, false);
}
__device__ __forceinline__ float tanh_f(float x) {
    float e = __expf(2.0f * x);
    return 1.0f - 2.0f * __builtin_amdgcn_rcpf(e + 1.0f);
}

// ---------------- K0: fp32 -> fp16 cvt (vector4) ----------------
__global__ void cvt_f32_f16(const float* __restrict__ src,
                            _Float16* __restrict__ dst, int n4) {
    int i = blockIdx.x * blockDim.x + threadIdx.x;
    int stride = gridDim.x * blockDim.x;
    for (; i < n4; i += stride) {
        float4 v = ((const float4*)src)[i];
        f16x2 a; a.x = (_Float16)v.x; a.y = (_Float16)v.y;
        f16x2 b; b.x = (_Float16)v.z; b.y = (_Float16)v.w;
        ((f16x2*)dst)[2 * i]     = a;
        ((f16x2*)dst)[2 * i + 1] = b;
    }
}

// ---------------- KG: xg[M,512] = A[M,K] . W[512,K]^T + (bih+bhh) ----------
// Block: 256 thr = 4 waves; wave w owns m16 tile (blk*64 + w*16), all 32 n-tiles.
// MFMA 16x16x32 f16. A/B fragments are direct b128 global loads:
//   frag lane l: row (l&15), k = ks*32 + (l>>4)*8 .. +8  (contiguous fp16).
// C/D: col=lane&15, row=(lane>>4)*4+reg  [measured: learn_hip m89].
__global__ __launch_bounds__(256, 1) void gemm_xg(
    const _Float16* __restrict__ A, const _Float16* __restrict__ W,
    const float* __restrict__ bih, const float* __restrict__ bhh,
    _Float16* __restrict__ out, int K)
{
    const int l  = threadIdx.x & 63;
    const int w  = threadIdx.x >> 6;
    const int mb = blockIdx.x * 64 + w * 16;
    const int c  = l & 15;       // tile col (n) / frag row
    const int q  = l >> 4;       // quad

    __shared__ float biasl[512];
    for (int i = threadIdx.x; i < 512; i += 256) biasl[i] = bih[i] + bhh[i];
    __syncthreads();

    f32x4 C[32];
    #pragma unroll
    for (int i = 0; i < 32; ++i) C[i] = (f32x4){0.f, 0.f, 0.f, 0.f};

    const int nks = K >> 5;
    for (int ks = 0; ks < nks; ++ks) {
        f16x8 Af = *(const f16x8*)(A + (size_t)(mb + c) * K + ks * 32 + q * 8);
        #pragma unroll
        for (int nt = 0; nt < 32; ++nt) {
            f16x8 Bf = *(const f16x8*)(W + (size_t)(nt * 16 + c) * K + ks * 32 + q * 8);
            C[nt] = __builtin_amdgcn_mfma_f32_16x16x32_f16(Af, Bf, C[nt], 0, 0, 0);
        }
    }
    // epilogue: bias + cvt + fp16 stores (quad-contiguous 32B segments)
    #pragma unroll
    for (int nt = 0; nt < 32; ++nt) {
        float bv = biasl[nt * 16 + c];
        #pragma unroll
        for (int i = 0; i < 4; ++i) {
            int row = mb + q * 4 + i;
            out[(size_t)row * 512 + nt * 16 + c] = (_Float16)(C[nt][i] + bv);
        }
    }
}

// ---------------- KR: one recurrent layer ----------------
// flags bit0: write h to h_out (layer0); bit1: final-step FC -> out (layer1)
__global__ __launch_bounds__(512, 2) void lstm_rec(
    const float* __restrict__ whh,      // [512,128] fp32
    const _Float16* __restrict__ xg,    // [B*T,512] fp16 (bias included)
    _Float16* __restrict__ h_out,       // [B*T,128] fp16
    const float* __restrict__ fc_w, const float* __restrict__ fc_b,
    float* __restrict__ out, int flags)
{
    const int t = threadIdx.x;          // gate row 0..511
    const int b = blockIdx.x;
    const int s = t & 1;                // K-half

    __shared__ __align__(16) _Float16 hbuf[128];
    __shared__ float gacts[512];
    __shared__ __align__(16) float h1f[128];

    // resident weights: rows t and t^1, K-half s => 64 VGPRs total
    f16x2 w0[32], w1[32];
    {
        const float4* r0 = (const float4*)(whh + t * 128 + s * 64);
        const float4* r1 = (const float4*)(whh + (t ^ 1) * 128 + s * 64);
        #pragma unroll
        for (int k = 0; k < 16; ++k) {
            float4 v = r0[k];
            w0[2 * k].x     = (_Float16)v.x; w0[2 * k].y     = (_Float16)v.y;
            w0[2 * k + 1].x = (_Float16)v.z; w0[2 * k + 1].y = (_Float16)v.w;
            float4 u = r1[k];
            w1[2 * k].x     = (_Float16)u.x; w1[2 * k].y     = (_Float16)u.y;
            w1[2 * k + 1].x = (_Float16)u.z; w1[2 * k + 1].y = (_Float16)u.w;
        }
    }
    if (t < 64) ((f16x2*)hbuf)[t] = (f16x2){(_Float16)0.f, (_Float16)0.f};
    __syncthreads();

    float c = 0.f;
    const _Float16* xgp = xg + (size_t)b * TT * 512 + t;
    _Float16 xcur = xgp[0];
    const f16x8* __restrict__ hv = (const f16x8*)(hbuf + s * 64);  // 8 chunks

    #pragma unroll 1
    for (int step = 0; step < TT; ++step) {
        _Float16 xnext = (step + 1 < TT) ? xgp[(size_t)(step + 1) * 512]
                                         : (_Float16)0.f;
        float a0 = 0.f, a1 = 0.f, p0 = 0.f, p1 = 0.f;
        #pragma unroll
        for (int ch = 0; ch < 8; ++ch) {
            f16x8 h = hv[ch];
            a0 = fdot2_(SH2(h, 0), w0[4 * ch + 0], a0);
            p0 = fdot2_(SH2(h, 0), w1[4 * ch + 0], p0);
            a1 = fdot2_(SH2(h, 1), w0[4 * ch + 1], a1);
            p1 = fdot2_(SH2(h, 1), w1[4 * ch + 1], p1);
            a0 = fdot2_(SH2(h, 2), w0[4 * ch + 2], a0);
            p0 = fdot2_(SH2(h, 2), w1[4 * ch + 2], p0);
            a1 = fdot2_(SH2(h, 3), w0[4 * ch + 3], a1);
            p1 = fdot2_(SH2(h, 3), w1[4 * ch + 3], p1);
        }
        float own   = a0 + a1;                    // P(row t,   half s)
        float other = p0 + p1;                    // P(row t^1, half s)
        float recv  = __shfl_xor(other, 1, 64);   // P(row t,   half s^1)
        float pre   = own + recv + (float)xcur;

        bool isg = (t >= 256) & (t < 384);        // g-gate -> tanh
        float zz = isg ? 2.f * pre : pre;
        float e  = __expf(-zz);
        float sg = __builtin_amdgcn_rcpf(1.f + e);
        gacts[t] = isg ? 2.f * sg - 1.f : sg;
        __syncthreads();  // B1: gacts ready; all hbuf reads done

        if (t < 128) {
            float gi = gacts[t],       gf = gacts[t + 128];
            float gg = gacts[t + 256], go = gacts[t + 384];
            c = gf * c + gi * gg;
            float hh = go * tanh_f(c);
            _Float16 h16 = (_Float16)hh;
            hbuf[t] = h16;
            if (flags & 1)
                h_out[((size_t)b * TT + step) * 128 + t] = h16;
            if ((flags & 2) && step == TT - 1) h1f[t] = hh;
        }
        __syncthreads();  // B2: new h visible
        xcur = xnext;
    }

    if (flags & 2) {
        if (t < 64) {
            float p = h1f[t] * fc_w[t] + h1f[t + 64] * fc_w[t + 64];
            #pragma unroll
            for (int off = 32; off > 0; off >>= 1) p += __shfl_down(p, off, 64);
            if (t == 0) out[b] = p + fc_b[0];
        }
    }
}

extern "C" void kernel_launch(void* const* d_in, const int* in_sizes, int n_in,
                              void* d_out, int out_size, void* d_ws, size_t ws_size,
                              hipStream_t stream) {
    const float* x     = (const float*)d_in[0];
    const float* w_ih0 = (const float*)d_in[1];
    const float* w_hh0 = (const float*)d_in[2];
    const float* b_ih0 = (const float*)d_in[3];
    const float* b_hh0 = (const float*)d_in[4];
    const float* w_ih1 = (const float*)d_in[5];
    const float* w_hh1 = (const float*)d_in[6];
    const float* b_ih1 = (const float*)d_in[7];
    const float* b_hh1 = (const float*)d_in[8];
    const float* fc_w  = (const float*)d_in[9];
    const float* fc_b  = (const float*)d_in[10];
    float* out = (float*)d_out;

    // ws layout (bytes)
    char* ws = (char*)d_ws;
    _Float16* xg     = (_Float16*)(ws);                            // 134217728
    _Float16* h0_all = (_Float16*)(ws + 134217728);                //  33554432
    _Float16* x16    = (_Float16*)(ws + 134217728 + 33554432);     //  16777216
    _Float16* w0_16  = (_Float16*)(ws + 134217728 + 33554432 + 16777216);          // 65536
    _Float16* w1_16  = (_Float16*)(ws + 134217728 + 33554432 + 16777216 + 65536);  // 131072

    // K0: conversions
    cvt_f32_f16<<<dim3(1024), dim3(256), 0, stream>>>(x, x16, (256 * 512 * 64) / 4);
    cvt_f32_f16<<<dim3(32), dim3(256), 0, stream>>>(w_ih0, w0_16, (512 * 64) / 4);
    cvt_f32_f16<<<dim3(64), dim3(256), 0, stream>>>(w_ih1, w1_16, (512 * 128) / 4);

    // KG: xg0 = x16 . Wih0^T + (b_ih0 + b_hh0)
    gemm_xg<<<dim3(MM / 64), dim3(256), 0, stream>>>(x16, w0_16, b_ih0, b_hh0, xg, 64);

    // KR: layer 0 (writes h0_all)
    lstm_rec<<<dim3(256), dim3(512), 0, stream>>>(w_hh0, xg, h0_all,
                                                  fc_w, fc_b, out, 1);

    // KG: xg1 = h0_all . Wih1^T + (b_ih1 + b_hh1)  (reuses xg buffer)
    gemm_xg<<<dim3(MM / 64), dim3(256), 0, stream>>>(h0_all, w1_16, b_ih1, b_hh1, xg, 128);

    // KR: layer 1 (+ fused FC)
    lstm_rec<<<dim3(256), dim3(512), 0, stream>>>(w_hh1, xg, h0_all,
                                                  fc_w, fc_b, out, 2);
}